// Round 14
// baseline (17.550 us; speedup 1.0000x reference)
//
#include <hip/hip_runtime.h>
#include <math.h>

#define BATCH 128
#define N_IN 2048
#define N_OUT 1024
#define MAXK 40
#define BCAP 64
#define TEMP 0.1f
#define INV_TEMP 10.0f
#define NEG_FILL -1.0e9f
#define WLO -0.1875f
#define WHI 0.1875f
#define BINSCALE 682.6666666f  // 256 / (WHI - WLO)

__device__ __forceinline__ unsigned int f2key(float f) {
    unsigned int b = __float_as_uint(f);
    return (b & 0x80000000u) ? ~b : (b | 0x80000000u);
}
__device__ __forceinline__ float key2f(unsigned int u) {
    unsigned int b = (u & 0x80000000u) ? (u & 0x7FFFFFFFu) : ~u;
    return __uint_as_float(b);
}

// K1, grid = N_OUT/2 = 512 blocks of 256: PURE dual-row compaction.
// Reads 2 mask rows, dual packed shfl-scan, control-dependent weight gather
// (~15/row; skips 99% of w), writes entry-major listsT[j][o]. No stragglers.
__global__ __launch_bounds__(256) void k_compact(const float* __restrict__ w,
                                                 const float* __restrict__ msk,
                                                 int* __restrict__ cnt,
                                                 int2* __restrict__ listsT) {
    __shared__ unsigned int wscr[4];
    __shared__ int sidx[2][MAXK];

    const int tid = threadIdx.x;
    const int lane = tid & 63;
    const int wvid = tid >> 6;
    const int o0 = (int)blockIdx.x * 2;

    const float4* m0 = (const float4*)(msk + (size_t)o0 * N_IN);
    const float4* m1 = (const float4*)(msk + (size_t)(o0 + 1) * N_IN);
    float4 m0a = m0[tid], m0b = m0[tid + 256];
    float4 m1a = m1[tid], m1b = m1[tid + 256];
    float mv0[8] = {m0a.x, m0a.y, m0a.z, m0a.w, m0b.x, m0b.y, m0b.z, m0b.w};
    float mv1[8] = {m1a.x, m1a.y, m1a.z, m1a.w, m1b.x, m1b.y, m1b.z, m1b.w};

    int c0 = 0, c1 = 0;
#pragma unroll
    for (int j = 0; j < 8; ++j) {
        c0 += (mv0[j] != 0.0f) ? 1 : 0;
        c1 += (mv1[j] != 0.0f) ? 1 : 0;
    }
    int packed = (c0 << 16) | c1;
    int sv = packed;
#pragma unroll
    for (int off = 1; off < 64; off <<= 1) {
        int t = __shfl_up(sv, off, 64);
        if (lane >= off) sv += t;
    }
    if (lane == 63) wscr[wvid] = (unsigned int)sv;
    __syncthreads();
    int base = 0;
    for (int ww = 0; ww < wvid; ++ww) base += (int)wscr[ww];
    const int excl = base + sv - packed;
    const int tot = (int)(wscr[0] + wscr[1] + wscr[2] + wscr[3]);
    const int ct0 = tot >> 16;
    const int ct1 = tot & 0xFFFF;
    if (tid == 0) {
        cnt[o0] = ct0;
        cnt[o0 + 1] = ct1;
    }

    int p0 = (excl >> 16) & 0xFFFF;
    int p1 = excl & 0xFFFF;
#pragma unroll
    for (int j = 0; j < 8; ++j) {
        const int idx = (j < 4) ? 4 * tid + j : 1024 + 4 * tid + (j - 4);
        if (mv0[j] != 0.0f) {
            if (p0 < MAXK) sidx[0][p0] = idx;
            ++p0;
        }
        if (mv1[j] != 0.0f) {
            if (p1 < MAXK) sidx[1][p1] = idx;
            ++p1;
        }
    }
    __syncthreads();

    // control-dependent weight gather (disjoint thread ranges -> real loads only)
    const int cc0 = (ct0 < MAXK) ? ct0 : MAXK;
    const int cc1 = (ct1 < MAXK) ? ct1 : MAXK;
    if (tid < cc0) {
        const int idx = sidx[0][tid];
        listsT[tid * N_OUT + o0] = make_int2(idx, __float_as_int(w[(size_t)o0 * N_IN + idx]));
    } else if (tid >= 64 && tid - 64 < cc1) {
        const int idx = sidx[1][tid - 64];
        listsT[(tid - 64) * N_OUT + (o0 + 1)] =
            make_int2(idx, __float_as_int(w[(size_t)(o0 + 1) * N_IN + idx]));
    }
}

// K2, grid = BATCH*2 blocks of 512: block (b, half). Loads x row b (float4
// per thread), computes the EXACT lower median in-block (binned select;
// 512-thread radix fallback), gates into LDS, then online sparse LSE — one
// output per thread.
__global__ __launch_bounds__(512) void k_mlse(const float* __restrict__ x,
                                              const int* __restrict__ cnt,
                                              const int2* __restrict__ listsT,
                                              const float* __restrict__ w,
                                              const float* __restrict__ msk,
                                              float* __restrict__ out) {
    __shared__ float sgx[N_IN];
    __shared__ unsigned int hist[256];
    __shared__ unsigned int wscr[8];
    __shared__ unsigned int sel[2];
    __shared__ float sbin[BCAP];
    __shared__ int s_nb;
    __shared__ float s_med;

    const int b = (int)blockIdx.x >> 1;
    const int h = (int)blockIdx.x & 1;
    const int tid = threadIdx.x;
    const int lane = tid & 63;
    const int wvid = tid >> 6;  // 0..7

    const float4* xr = (const float4*)(x + (size_t)b * N_IN);
    float4 va = xr[tid];  // 512 threads x 4 = 2048
    float vals[4] = {va.x, va.y, va.z, va.w};

    if (tid < 256) hist[tid] = 0;
    if (tid == 0) s_nb = 0;
    __syncthreads();

    // pass 1: count below window; histogram in-window values
    int cb = 0;
#pragma unroll
    for (int j = 0; j < 4; ++j) {
        float v = vals[j];
        cb += (v < WLO) ? 1 : 0;
        if (v >= WLO && v < WHI) {
            int bin = (int)((v - WLO) * BINSCALE);
            bin = (bin > 255) ? 255 : bin;
            atomicAdd(&hist[bin], 1u);
        }
    }
    int sb = cb;
#pragma unroll
    for (int off = 1; off < 64; off <<= 1) sb += __shfl_xor(sb, off, 64);
    if (lane == 0) wscr[wvid] = (unsigned int)sb;
    __syncthreads();
    int c_lo = 0;
#pragma unroll
    for (int ww = 0; ww < 8; ++ww) c_lo += (int)wscr[ww];
    const int R = (N_IN - 1) / 2 - c_lo;  // lower-median rank in window
    __syncthreads();  // wscr about to be reused by the scan

    // inclusive scan of 256-bin histogram (threads 0..255 = waves 0..3)
    unsigned int hv = 0, sv = 0;
    if (tid < 256) {
        hv = hist[tid];
        sv = hv;
#pragma unroll
        for (int off = 1; off < 64; off <<= 1) {
            unsigned int t = __shfl_up(sv, off, 64);
            if (lane >= off) sv += t;
        }
        if (lane == 63) wscr[wvid] = sv;
    }
    if (tid == 0) sel[0] = 0xFFFFFFFFu;
    __syncthreads();
    const int n_c = (int)(wscr[0] + wscr[1] + wscr[2] + wscr[3]);
    if (tid < 256) {
        unsigned int base = 0;
        for (int ww = 0; ww < wvid; ++ww) base += wscr[ww];
        const unsigned int incl = sv + base;
        const unsigned int excl = incl - hv;
        if (R >= 0 && R < n_c && (unsigned int)R >= excl && (unsigned int)R < incl) {
            sel[0] = (unsigned int)tid;       // target bin
            sel[1] = (unsigned int)R - excl;  // rank within bin
        }
    }
    __syncthreads();

    bool fast_ok = (R >= 0 && R < n_c && sel[0] != 0xFFFFFFFFu);
    if (fast_ok) {
        const int B = (int)sel[0];
        const int r2 = (int)sel[1];
#pragma unroll
        for (int j = 0; j < 4; ++j) {  // compact target bin (~1-3 elems)
            float v = vals[j];
            if (v >= WLO && v < WHI) {
                int bin = (int)((v - WLO) * BINSCALE);
                bin = (bin > 255) ? 255 : bin;
                if (bin == B) {
                    int p = atomicAdd(&s_nb, 1);
                    if (p < BCAP) sbin[p] = v;
                }
            }
        }
        __syncthreads();
        const int nb = s_nb;
        if (nb <= BCAP) {
            if (tid < nb) {
                float v = sbin[tid];
                int nlt = 0, neq = 0;
                for (int j = 0; j < nb; ++j) {
                    float u = sbin[j];
                    nlt += (u < v) ? 1 : 0;
                    neq += (u == v) ? 1 : 0;
                }
                if (nlt <= r2 && r2 < nlt + neq) s_med = v;  // ties agree
            }
        } else {
            fast_ok = false;
        }
        __syncthreads();
    }
    if (!fast_ok) {
        // exact 4-pass radix select fallback (512-thread variant)
        unsigned int prefix = 0;
        unsigned int k = (N_IN - 1) / 2;
        for (int pos = 24; pos >= 0; pos -= 8) {
            if (tid < 256) hist[tid] = 0;
            __syncthreads();
            const unsigned int hmask = (pos == 24) ? 0u : (0xFFFFFFFFu << (pos + 8));
#pragma unroll
            for (int j = 0; j < 4; ++j) {
                unsigned int u = f2key(vals[j]);
                if ((u & hmask) == (prefix & hmask))
                    atomicAdd(&hist[(u >> pos) & 0xFFu], 1u);
            }
            __syncthreads();
            unsigned int v = 0, s2 = 0;
            if (tid < 256) {
                v = hist[tid];
                s2 = v;
#pragma unroll
                for (int off = 1; off < 64; off <<= 1) {
                    unsigned int t = __shfl_up(s2, off, 64);
                    if (lane >= off) s2 += t;
                }
            }
            __syncthreads();  // protect wscr reuse
            if (tid < 256 && lane == 63) wscr[wvid] = s2;
            __syncthreads();
            if (tid < 256) {
                unsigned int bs = 0;
                for (int ww = 0; ww < wvid; ++ww) bs += wscr[ww];
                const unsigned int inc2 = s2 + bs;
                const unsigned int exc2 = inc2 - v;
                if (k >= exc2 && k < inc2) {
                    sel[0] = (unsigned int)tid;
                    sel[1] = k - exc2;
                }
            }
            __syncthreads();
            prefix |= sel[0] << pos;
            k = sel[1];
            __syncthreads();
        }
        if (tid == 0) s_med = key2f(prefix);
        __syncthreads();
    }
    const float med = s_med;

    // gate into LDS
    float4 ga;
    ga.x = (fabsf(vals[0] - med) < 1.0f) ? vals[0] : 0.0f;
    ga.y = (fabsf(vals[1] - med) < 1.0f) ? vals[1] : 0.0f;
    ga.z = (fabsf(vals[2] - med) < 1.0f) ? vals[2] : 0.0f;
    ga.w = (fabsf(vals[3] - med) < 1.0f) ? vals[3] : 0.0f;
    ((float4*)sgx)[tid] = ga;
    __syncthreads();

    // online sparse LSE: one output per thread
    const int o = h * 512 + tid;
    const int c = cnt[o];
    float res;
    if (c == 0) {
        res = NEG_FILL;  // T*(-1e10 + log 2048) rounds to -1e9 in f32
    } else if (c <= MAXK) {
        int2 e = listsT[o];  // j=0; coalesced across lanes
        float m = (sgx[e.x] + __int_as_float(e.y)) * INV_TEMP;
        float s = 1.0f;
        for (int j = 1; j < c; ++j) {
            e = listsT[j * N_OUT + o];
            float v = (sgx[e.x] + __int_as_float(e.y)) * INV_TEMP;
            float mn = fmaxf(m, v);
            s = s * __expf(m - mn) + __expf(v - mn);
            m = mn;
        }
        res = TEMP * (m + __logf(s));
    } else {
        // overflow fallback (statistically unreachable): dense masked pass
        const float* mr = msk + (size_t)o * N_IN;
        const float* wr = w + (size_t)o * N_IN;
        float m = -INFINITY, s = 0.0f;
        for (int i = 0; i < N_IN; ++i) {
            if (mr[i] != 0.0f) {
                float v = (sgx[i] + wr[i]) * INV_TEMP;
                float mn = fmaxf(m, v);
                s = s * __expf(m - mn) + __expf(v - mn);
                m = mn;
            }
        }
        res = TEMP * (m + __logf(s));
    }
    out[(size_t)b * N_OUT + o] = res;
}

extern "C" void kernel_launch(void* const* d_in, const int* in_sizes, int n_in,
                              void* d_out, int out_size, void* d_ws, size_t ws_size,
                              hipStream_t stream) {
    const float* x = (const float*)d_in[0];
    const float* w = (const float*)d_in[1];
    const float* msk = (const float*)d_in[2];
    float* out = (float*)d_out;

    int* cnt = (int*)d_ws;                // N_OUT ints
    int2* listsT = (int2*)(cnt + N_OUT);  // MAXK*N_OUT int2 (320 KB)

    hipLaunchKernelGGL(k_compact, dim3(N_OUT / 2), dim3(256), 0, stream,
                       w, msk, cnt, listsT);
    hipLaunchKernelGGL(k_mlse, dim3(BATCH * 2), dim3(512), 0, stream,
                       x, cnt, listsT, w, msk, out);
}

// Round 15
// 16.087 us; speedup vs baseline: 1.0909x; 1.0909x over previous
//
#include <hip/hip_runtime.h>
#include <math.h>

#define BATCH 128
#define N_IN 2048
#define N_OUT 1024
#define MAXK 40
#define BCAP 64
#define TEMP 0.1f
#define INV_TEMP 10.0f
#define NEG_FILL -1.0e9f
#define WLO -0.1875f
#define WHI 0.1875f
#define BINSCALE 682.6666666f  // 256 / (WHI - WLO)

__device__ __forceinline__ unsigned int f2key(float f) {
    unsigned int b = __float_as_uint(f);
    return (b & 0x80000000u) ? ~b : (b | 0x80000000u);
}
__device__ __forceinline__ float key2f(unsigned int u) {
    unsigned int b = (u & 0x80000000u) ? (u & 0x7FFFFFFFu) : ~u;
    return __uint_as_float(b);
}

// K1, grid = BATCH + N_OUT/2 = 640 blocks.
//  bid < BATCH: exact lower-median of x row b -> med[b] (binned exact select;
//    radix fallback keeps exactness data-independent). Latency phases hide
//    under the 512 BW-bound compaction blocks.
//  bid >= BATCH: dual-row compaction, single-phase: the w[o][idx] load sits
//    INSIDE the if(mask!=0) branch (control-dependent -> never speculated ->
//    only ~15/2048 weights actually read). One barrier total.
__global__ __launch_bounds__(256) void k_prep(const float* __restrict__ x,
                                              const float* __restrict__ w,
                                              const float* __restrict__ msk,
                                              int* __restrict__ cnt,
                                              int2* __restrict__ listsT,
                                              float* __restrict__ med) {
    __shared__ unsigned int hist[256];
    __shared__ unsigned int wscr[4];
    __shared__ unsigned int sel[2];
    __shared__ float sbin[BCAP];
    __shared__ int s_nb;
    __shared__ float s_med;

    const int tid = threadIdx.x;
    const int lane = tid & 63;
    const int wvid = tid >> 6;
    const int bid = (int)blockIdx.x;

    if (bid < BATCH) {
        // ================== exact lower median (proven R8/R13 path) ==================
        const float4* xr = (const float4*)(x + (size_t)bid * N_IN);
        float4 va = xr[tid], vb = xr[tid + 256];
        float vals[8] = {va.x, va.y, va.z, va.w, vb.x, vb.y, vb.z, vb.w};

        hist[tid] = 0;
        if (tid == 0) s_nb = 0;
        __syncthreads();

        int cb = 0;
#pragma unroll
        for (int j = 0; j < 8; ++j) {
            float v = vals[j];
            cb += (v < WLO) ? 1 : 0;
            if (v >= WLO && v < WHI) {
                int bin = (int)((v - WLO) * BINSCALE);
                bin = (bin > 255) ? 255 : bin;
                atomicAdd(&hist[bin], 1u);
            }
        }
        int sb = cb;
#pragma unroll
        for (int off = 1; off < 64; off <<= 1) sb += __shfl_xor(sb, off, 64);
        if (lane == 0) wscr[wvid] = (unsigned int)sb;
        __syncthreads();
        const int c_lo = (int)(wscr[0] + wscr[1] + wscr[2] + wscr[3]);
        const int R = (N_IN - 1) / 2 - c_lo;

        unsigned int hv = hist[tid];
        unsigned int sv = hv;
#pragma unroll
        for (int off = 1; off < 64; off <<= 1) {
            unsigned int t = __shfl_up(sv, off, 64);
            if (lane >= off) sv += t;
        }
        __syncthreads();
        if (lane == 63) wscr[wvid] = sv;
        if (tid == 0) sel[0] = 0xFFFFFFFFu;
        __syncthreads();
        unsigned int base = 0;
        for (int ww = 0; ww < wvid; ++ww) base += wscr[ww];
        const unsigned int incl = sv + base;
        const unsigned int excl = incl - hv;
        const int n_c = (int)(wscr[0] + wscr[1] + wscr[2] + wscr[3]);
        if (R >= 0 && R < n_c && (unsigned int)R >= excl && (unsigned int)R < incl) {
            sel[0] = (unsigned int)tid;
            sel[1] = (unsigned int)R - excl;
        }
        __syncthreads();

        bool fast_ok = (R >= 0 && R < n_c && sel[0] != 0xFFFFFFFFu);
        if (fast_ok) {
            const int B = (int)sel[0];
            const int r2 = (int)sel[1];
#pragma unroll
            for (int j = 0; j < 8; ++j) {
                float v = vals[j];
                if (v >= WLO && v < WHI) {
                    int bin = (int)((v - WLO) * BINSCALE);
                    bin = (bin > 255) ? 255 : bin;
                    if (bin == B) {
                        int p = atomicAdd(&s_nb, 1);
                        if (p < BCAP) sbin[p] = v;
                    }
                }
            }
            __syncthreads();
            const int nb = s_nb;
            if (nb <= BCAP) {
                if (tid < nb) {
                    float v = sbin[tid];
                    int nlt = 0, neq = 0;
                    for (int j = 0; j < nb; ++j) {
                        float u = sbin[j];
                        nlt += (u < v) ? 1 : 0;
                        neq += (u == v) ? 1 : 0;
                    }
                    if (nlt <= r2 && r2 < nlt + neq) s_med = v;  // ties agree
                }
            } else {
                fast_ok = false;
            }
            __syncthreads();
        }
        if (!fast_ok) {
            // exact 4-pass radix select fallback
            unsigned int prefix = 0;
            unsigned int k = (N_IN - 1) / 2;
            for (int pos = 24; pos >= 0; pos -= 8) {
                hist[tid] = 0;
                __syncthreads();
                const unsigned int hmask = (pos == 24) ? 0u : (0xFFFFFFFFu << (pos + 8));
#pragma unroll
                for (int j = 0; j < 8; ++j) {
                    unsigned int u = f2key(vals[j]);
                    if ((u & hmask) == (prefix & hmask))
                        atomicAdd(&hist[(u >> pos) & 0xFFu], 1u);
                }
                __syncthreads();
                unsigned int v = hist[tid];
                unsigned int s2 = v;
#pragma unroll
                for (int off = 1; off < 64; off <<= 1) {
                    unsigned int t = __shfl_up(s2, off, 64);
                    if (lane >= off) s2 += t;
                }
                if (lane == 63) wscr[wvid] = s2;
                __syncthreads();
                unsigned int bs = 0;
                for (int ww = 0; ww < wvid; ++ww) bs += wscr[ww];
                const unsigned int inc2 = s2 + bs;
                const unsigned int exc2 = inc2 - v;
                if (k >= exc2 && k < inc2) {
                    sel[0] = (unsigned int)tid;
                    sel[1] = k - exc2;
                }
                __syncthreads();
                prefix |= sel[0] << pos;
                k = sel[1];
                __syncthreads();
            }
            if (tid == 0) s_med = key2f(prefix);
            __syncthreads();
        }
        if (tid == 0) med[bid] = s_med;
    } else {
        // ====== dual-row compaction, single phase, branch-guarded w gather ======
        const int o0 = (bid - BATCH) * 2;
        const float4* m0 = (const float4*)(msk + (size_t)o0 * N_IN);
        const float4* m1 = (const float4*)(msk + (size_t)(o0 + 1) * N_IN);
        float4 m0a = m0[tid], m0b = m0[tid + 256];
        float4 m1a = m1[tid], m1b = m1[tid + 256];
        float mv0[8] = {m0a.x, m0a.y, m0a.z, m0a.w, m0b.x, m0b.y, m0b.z, m0b.w};
        float mv1[8] = {m1a.x, m1a.y, m1a.z, m1a.w, m1b.x, m1b.y, m1b.z, m1b.w};
        const float* wr0 = w + (size_t)o0 * N_IN;
        const float* wr1 = wr0 + N_IN;

        int c0 = 0, c1 = 0;
#pragma unroll
        for (int j = 0; j < 8; ++j) {
            c0 += (mv0[j] != 0.0f) ? 1 : 0;
            c1 += (mv1[j] != 0.0f) ? 1 : 0;
        }
        int packed = (c0 << 16) | c1;
        int sv = packed;
#pragma unroll
        for (int off = 1; off < 64; off <<= 1) {
            int t = __shfl_up(sv, off, 64);
            if (lane >= off) sv += t;
        }
        if (lane == 63) wscr[wvid] = (unsigned int)sv;
        __syncthreads();
        int base = 0;
        for (int ww = 0; ww < wvid; ++ww) base += (int)wscr[ww];
        const int excl = base + sv - packed;
        const int tot = (int)(wscr[0] + wscr[1] + wscr[2] + wscr[3]);
        if (tid == 0) {
            cnt[o0] = tot >> 16;
            cnt[o0 + 1] = tot & 0xFFFF;
        }

        // single pass: list write (idx + weight) directly under the mask branch.
        // The w load is control-dependent -> compiler cannot speculate it.
        int p0 = (excl >> 16) & 0xFFFF;
        int p1 = excl & 0xFFFF;
#pragma unroll
        for (int j = 0; j < 8; ++j) {
            const int idx = (j < 4) ? 4 * tid + j : 1024 + 4 * tid + (j - 4);
            if (mv0[j] != 0.0f) {
                if (p0 < MAXK)
                    listsT[p0 * N_OUT + o0] = make_int2(idx, __float_as_int(wr0[idx]));
                ++p0;
            }
            if (mv1[j] != 0.0f) {
                if (p1 < MAXK)
                    listsT[p1 * N_OUT + (o0 + 1)] = make_int2(idx, __float_as_int(wr1[idx]));
                ++p1;
            }
        }
    }
}

// K2, grid = BATCH*2 blocks of 512: block (b, half); one output per thread.
// Stage gated x row in LDS once, then online sparse LSE (proven R13 path).
__global__ __launch_bounds__(512) void k_lse(const float* __restrict__ x,
                                             const float* __restrict__ medv,
                                             const int* __restrict__ cnt,
                                             const int2* __restrict__ listsT,
                                             const float* __restrict__ w,
                                             const float* __restrict__ msk,
                                             float* __restrict__ out) {
    __shared__ float sgx[N_IN];
    const int b = (int)blockIdx.x >> 1;
    const int h = (int)blockIdx.x & 1;
    const int tid = threadIdx.x;

    const float med = medv[b];
    const float4* xr = (const float4*)(x + (size_t)b * N_IN);
    float4 va = xr[tid];  // 512 threads x float4 = 2048 floats
    float4 ga;
    ga.x = (fabsf(va.x - med) < 1.0f) ? va.x : 0.0f;
    ga.y = (fabsf(va.y - med) < 1.0f) ? va.y : 0.0f;
    ga.z = (fabsf(va.z - med) < 1.0f) ? va.z : 0.0f;
    ga.w = (fabsf(va.w - med) < 1.0f) ? va.w : 0.0f;
    ((float4*)sgx)[tid] = ga;
    __syncthreads();

    const int o = h * 512 + tid;
    const int c = cnt[o];
    float res;
    if (c == 0) {
        res = NEG_FILL;  // T*(-1e10 + log 2048) rounds to -1e9 in f32
    } else if (c <= MAXK) {
        int2 e = listsT[o];  // j=0; coalesced across lanes
        float m = (sgx[e.x] + __int_as_float(e.y)) * INV_TEMP;
        float s = 1.0f;
        for (int j = 1; j < c; ++j) {  // online LSE: one pass, exact rescale
            e = listsT[j * N_OUT + o];
            float v = (sgx[e.x] + __int_as_float(e.y)) * INV_TEMP;
            float mn = fmaxf(m, v);
            s = s * __expf(m - mn) + __expf(v - mn);
            m = mn;
        }
        res = TEMP * (m + __logf(s));
    } else {
        // overflow fallback (statistically unreachable): dense masked pass
        const float* mr = msk + (size_t)o * N_IN;
        const float* wr = w + (size_t)o * N_IN;
        float m = -INFINITY, s = 0.0f;
        for (int i = 0; i < N_IN; ++i) {
            if (mr[i] != 0.0f) {
                float v = (sgx[i] + wr[i]) * INV_TEMP;
                float mn = fmaxf(m, v);
                s = s * __expf(m - mn) + __expf(v - mn);
                m = mn;
            }
        }
        res = TEMP * (m + __logf(s));
    }
    out[(size_t)b * N_OUT + o] = res;
}

extern "C" void kernel_launch(void* const* d_in, const int* in_sizes, int n_in,
                              void* d_out, int out_size, void* d_ws, size_t ws_size,
                              hipStream_t stream) {
    const float* x = (const float*)d_in[0];
    const float* w = (const float*)d_in[1];
    const float* msk = (const float*)d_in[2];
    float* out = (float*)d_out;

    int* cnt = (int*)d_ws;                                 // N_OUT ints
    int2* listsT = (int2*)(cnt + N_OUT);                   // MAXK*N_OUT int2 (320 KB)
    float* med = (float*)(listsT + (size_t)MAXK * N_OUT);  // BATCH floats

    hipLaunchKernelGGL(k_prep, dim3(BATCH + N_OUT / 2), dim3(256), 0, stream,
                       x, w, msk, cnt, listsT, med);
    hipLaunchKernelGGL(k_lse, dim3(BATCH * 2), dim3(512), 0, stream,
                       x, med, cnt, listsT, w, msk, out);
}